// Round 8
// baseline (1925.612 us; speedup 1.0000x reference)
//
#include <hip/hip_runtime.h>
#include <hip/hip_bf16.h>
#include <stdint.h>

#define IN_SZ 128
#define HID 128
#define OUT_SZ 67
#define SEQ 512
#define BATCH 2048
#define SB (SEQ * BATCH)   // 1048576 elements

typedef __attribute__((ext_vector_type(4))) float f32x4;
typedef __attribute__((ext_vector_type(8))) short s16x8;
typedef __attribute__((ext_vector_type(8))) __bf16 bf16x8;

// setup-only scalar RNE
static __device__ __forceinline__ unsigned short f2bf(float f) {
  union { float f; uint32_t u; } c; c.f = f;
  uint32_t u = c.u;
  uint32_t r = u + 0x7FFFu + ((u >> 16) & 1u);
  return (unsigned short)(r >> 16);
}
// hot-loop packed convert -> v_cvt_pk_bf16_f32
static __device__ __forceinline__ uint32_t pk2bf(float lo, float hi) {
  __hip_bfloat162 h2 = __float22bfloat162_rn(float2{lo, hi});
  union { __hip_bfloat162 h; uint32_t u; } c; c.h = h2;
  return c.u;
}
// divide-free tanh
static __device__ __forceinline__ float fast_tanh(float x) {
  float e = __builtin_amdgcn_exp2f(x * 2.885390081777927f);
  float r = __builtin_amdgcn_rcpf(e + 1.f);
  return __builtin_fmaf(-2.f, r, 1.f);
}
// fragment k-offset for slot j (HW-verified R1-R7)
#define KOFF(g, j) (4 * (g) + ((j) & 3) + (((j) >> 2) << 4))

// i2h MFMA, A-operand pinned to AGPRs ("a" constraint). D != C init form.
static __device__ __forceinline__ f32x4 mfma_init_a(s16x8 a, s16x8 b, f32x4 c) {
  f32x4 d;
  asm("v_mfma_f32_16x16x32_bf16 %0, %1, %2, %3"
      : "=&v"(d) : "a"(a), "v"(b), "v"(c));
  return d;
}
static __device__ __forceinline__ void mfma_acc_a(f32x4& c, s16x8 a, s16x8 b) {
  asm("v_mfma_f32_16x16x32_bf16 %0, %1, %2, %0" : "+v"(c) : "a"(a), "v"(b));
}
// i2o via builtin (all-VGPR; compiler models hazards)
static __device__ __forceinline__ void mfma16(f32x4& c, s16x8 a, s16x8 b) {
  c = __builtin_amdgcn_mfma_f32_16x16x32_bf16(
        __builtin_bit_cast(bf16x8, a), __builtin_bit_cast(bf16x8, b), c, 0, 0, 0);
}
// MFMA->VALU hazard guard with true data dependencies (R2 lesson: deps, not volatility)
static __device__ __forceinline__ void guard8(f32x4& a0, f32x4& a1, f32x4& a2, f32x4& a3,
                                              f32x4& a4, f32x4& a5, f32x4& a6, f32x4& a7) {
  asm volatile("s_nop 7\n\ts_nop 7\n\ts_nop 7"
               : "+v"(a0), "+v"(a1), "+v"(a2), "+v"(a3),
                 "+v"(a4), "+v"(a5), "+v"(a6), "+v"(a7));
}

__global__ __launch_bounds__(64, 1) void rnn_kernel(
    const float* __restrict__ x, const float* __restrict__ hidden,
    const float* __restrict__ mask, const float* __restrict__ Wi2h,
    const float* __restrict__ bi2h, const float* __restrict__ Wi2o,
    const float* __restrict__ bi2o, float* __restrict__ Y) {

  __shared__ s16x8 sWO[20][64];   // i2o A-frags, 20.5 KB
  __shared__ float sBH[8][16];
  __shared__ float sBO[5][16];

  const int lane = threadIdx.x;
  const int g = lane >> 4;
  const int n16 = lane & 15;
  const int b0 = blockIdx.x * 16;

  // ---- Wi2h A-frags -> AGPRs (used only via "a" asm inputs) ----
  s16x8 WA[8][8];
#pragma unroll
  for (int tl = 0; tl < 8; ++tl) {
    const float* wrow = Wi2h + (size_t)(16 * tl + n16) * (IN_SZ + HID);
#pragma unroll
    for (int kt = 0; kt < 8; ++kt) {
      s16x8 w8;
#pragma unroll
      for (int j = 0; j < 8; ++j)
        w8[j] = (short)f2bf(wrow[32 * kt + KOFF(g, j)]);
      WA[tl][kt] = w8;
    }
  }

  // ---- LDS constants (single wave: no barrier; compiler orders ds ops) ----
#pragma unroll
  for (int tk = 0; tk < 20; ++tk) {
    int ot = tk >> 2, kk = tk & 3;
    int m = 16 * ot + n16;
    unsigned short v[8];
#pragma unroll
    for (int j = 0; j < 8; ++j) {
      int k = 32 * kk + KOFF(g, j);
      v[j] = (m < OUT_SZ) ? f2bf(Wi2o[(size_t)m * HID + k]) : (unsigned short)0;
    }
    sWO[tk][lane] = *(s16x8*)v;
  }
  if (lane < 16) {
#pragma unroll
    for (int tl = 0; tl < 8; ++tl) sBH[tl][lane] = bi2h[16 * tl + lane];
#pragma unroll
    for (int ot = 0; ot < 5; ++ot) {
      int m = 16 * ot + lane;
      sBO[ot][lane] = (m < OUT_SZ) ? bi2o[m] : 0.f;
    }
  }

  // opacified LDS pointers: defeats LICM hoisting of the per-step constant reads
  const s16x8* wop = &sWO[0][0];
  const float* bhp = &sBH[0][0];
  const float* bop = &sBO[0][0];

  // ---- addressing bases (uint32 element offsets) ----
  uint32_t bx[8];
#pragma unroll
  for (int j = 0; j < 8; ++j)
    bx[j] = (uint32_t)KOFF(g, j) * (uint32_t)SB + (uint32_t)(b0 + n16);
  uint32_t yb[5];
#pragma unroll
  for (int ot = 0; ot < 5; ++ot)
    yb[ot] = (uint32_t)(16 * ot + 4 * g) * (uint32_t)SB + (uint32_t)(b0 + n16);

  // ---- initial frags: Bx = x_0, Bh = hidden*mask ----
  s16x8 Bx[4], Bh[4];
#pragma unroll
  for (int kk = 0; kk < 4; ++kk) {
    float xv[8], hv[8];
#pragma unroll
    for (int j = 0; j < 8; ++j) {
      uint32_t row = (uint32_t)(32 * kk + KOFF(g, j));
      xv[j] = x[(size_t)(bx[j] + (uint32_t)(32 * kk) * SB)];
      uint32_t hoff = row * BATCH + (uint32_t)(b0 + n16);
      hv[j] = hidden[(size_t)hoff] * mask[(size_t)hoff];
    }
    union { s16x8 v; uint32_t d[4]; } ux, uh;
#pragma unroll
    for (int q = 0; q < 4; ++q) {
      ux.d[q] = pk2bf(xv[2 * q], xv[2 * q + 1]);
      uh.d[q] = pk2bf(hv[2 * q], hv[2 * q + 1]);
    }
    Bx[kk] = ux.v;
    Bh[kk] = uh.v;
  }

  // ---- raw x double-buffer: xcA = x_1 ----
  float xcA[32], xcB[32];
#pragma unroll
  for (int q = 0; q < 4; ++q)
#pragma unroll
    for (int j = 0; j < 8; ++j)
      xcA[8 * q + j] = x[(size_t)(bx[j] + (uint32_t)(32 * q) * SB + (uint32_t)BATCH)];

#define BODY(T, XC, XN)                                                          \
  {                                                                              \
    const int t = (T);                                                           \
    asm volatile("" : "+v"(wop), "+v"(bhp), "+v"(bop));                          \
    uint32_t tpre = (uint32_t)((t + 2 > SEQ - 1) ? SEQ - 1 : t + 2);             \
    uint32_t xoffT = tpre * (uint32_t)BATCH;                                     \
    _Pragma("unroll")                                                            \
    for (int q = 0; q < 4; ++q)                                                  \
      _Pragma("unroll")                                                          \
      for (int j = 0; j < 8; ++j)                                                \
        XN[8 * q + j] = x[(size_t)(bx[j] + xoffT + (uint32_t)(32 * q) * SB)];    \
    f32x4 acc[8];                                                                \
    _Pragma("unroll")                                                            \
    for (int tl = 0; tl < 8; ++tl) {                                             \
      f32x4 c = *(const f32x4*)(bhp + 16 * tl + 4 * g);                          \
      acc[tl] = mfma_init_a(WA[tl][0], Bx[0], c);                                \
    }                                                                            \
    _Pragma("unroll")                                                            \
    for (int kt = 1; kt < 4; ++kt)                                               \
      _Pragma("unroll")                                                          \
      for (int tl = 0; tl < 8; ++tl) mfma_acc_a(acc[tl], WA[tl][kt], Bx[kt]);    \
    _Pragma("unroll")                                                            \
    for (int kk = 0; kk < 4; ++kk)                                               \
      _Pragma("unroll")                                                          \
      for (int tl = 0; tl < 8; ++tl) mfma_acc_a(acc[tl], WA[tl][4 + kk], Bh[kk]);\
    guard8(acc[0], acc[1], acc[2], acc[3], acc[4], acc[5], acc[6], acc[7]);      \
    _Pragma("unroll")                                                            \
    for (int kk = 0; kk < 4; ++kk) {                                             \
      union { s16x8 v; uint32_t d[4]; } u;                                       \
      u.d[0] = pk2bf(fast_tanh(acc[2 * kk][0]), fast_tanh(acc[2 * kk][1]));      \
      u.d[1] = pk2bf(fast_tanh(acc[2 * kk][2]), fast_tanh(acc[2 * kk][3]));      \
      u.d[2] = pk2bf(fast_tanh(acc[2 * kk + 1][0]), fast_tanh(acc[2 * kk + 1][1]));\
      u.d[3] = pk2bf(fast_tanh(acc[2 * kk + 1][2]), fast_tanh(acc[2 * kk + 1][3]));\
      Bh[kk] = u.v;                                                              \
    }                                                                            \
    _Pragma("unroll")                                                            \
    for (int kk = 0; kk < 4; ++kk) {                                             \
      union { s16x8 v; uint32_t d[4]; } u;                                       \
      _Pragma("unroll")                                                          \
      for (int q = 0; q < 4; ++q)                                                \
        u.d[q] = pk2bf(XC[8 * kk + 2 * q], XC[8 * kk + 2 * q + 1]);              \
      Bx[kk] = u.v;                                                              \
    }                                                                            \
    uint32_t toffY = (uint32_t)t * (uint32_t)BATCH;                              \
    _Pragma("unroll")                                                            \
    for (int ot = 0; ot < 5; ++ot) {                                             \
      f32x4 ao = *(const f32x4*)(bop + 16 * ot + 4 * g);                         \
      _Pragma("unroll")                                                          \
      for (int kk = 0; kk < 4; ++kk) {                                           \
        s16x8 wf = wop[(ot * 4 + kk) * 64 + lane];                               \
        mfma16(ao, wf, Bh[kk]);                                                  \
      }                                                                          \
      _Pragma("unroll")                                                          \
      for (int r = 0; r < 4; ++r) {                                              \
        float v = fmaxf(ao[r], 0.f);                                             \
        uint32_t yi = yb[ot] + (uint32_t)r * (uint32_t)SB + toffY;               \
        if (ot < 4) Y[(size_t)yi] = v;                                           \
        else if (4 * g + r < 3) Y[(size_t)yi] = v;                               \
      }                                                                          \
    }                                                                            \
  }

  for (int t2 = 0; t2 < SEQ; t2 += 2) {
    BODY(t2, xcA, xcB);
    BODY(t2 + 1, xcB, xcA);
  }
#undef BODY
}

extern "C" void kernel_launch(void* const* d_in, const int* in_sizes, int n_in,
                              void* d_out, int out_size, void* d_ws, size_t ws_size,
                              hipStream_t stream) {
  const float* x      = (const float*)d_in[0];
  const float* hidden = (const float*)d_in[1];
  const float* mask   = (const float*)d_in[2];
  const float* Wi2h   = (const float*)d_in[3];
  const float* bi2h   = (const float*)d_in[4];
  const float* Wi2o   = (const float*)d_in[5];
  const float* bi2o   = (const float*)d_in[6];
  float* Y = (float*)d_out;
  (void)in_sizes; (void)n_in; (void)out_size; (void)d_ws; (void)ws_size;
  rnn_kernel<<<dim3(BATCH / 16), dim3(64), 0, stream>>>(
      x, hidden, mask, Wi2h, bi2h, Wi2o, bi2o, Y);
}

// Round 9
// 564.400 us; speedup vs baseline: 3.4118x; 3.4118x over previous
//
#include <hip/hip_runtime.h>
#include <hip/hip_bf16.h>
#include <stdint.h>

#define IN_SZ 128
#define HID 128
#define OUT_SZ 67
#define SEQ 512
#define BATCH 2048
#define BT 8
#define NTHR 256
#define SB (SEQ * BATCH)   // 1048576

typedef __attribute__((ext_vector_type(4))) float f32x4;
typedef __attribute__((ext_vector_type(8))) short s16x8;
typedef __attribute__((ext_vector_type(8))) __bf16 bf16x8;

// setup-only scalar RNE
static __device__ __forceinline__ unsigned short f2bf(float f) {
  union { float f; uint32_t u; } c; c.f = f;
  uint32_t u = c.u;
  uint32_t r = u + 0x7FFFu + ((u >> 16) & 1u);
  return (unsigned short)(r >> 16);
}
// hot-loop packed convert -> v_cvt_pk_bf16_f32
static __device__ __forceinline__ uint32_t pk2bf(float lo, float hi) {
  __hip_bfloat162 h2 = __float22bfloat162_rn(float2{lo, hi});
  union { __hip_bfloat162 h; uint32_t u; } c; c.h = h2;
  return c.u;
}
// divide-free tanh (validated R7: absmax 7.8e-3)
static __device__ __forceinline__ float fast_tanh(float x) {
  float e = __builtin_amdgcn_exp2f(x * 2.885390081777927f);
  float r = __builtin_amdgcn_rcpf(e + 1.f);
  return __builtin_fmaf(-2.f, r, 1.f);
}
static __device__ __forceinline__ void mfma16(f32x4& c, s16x8 a, s16x8 b) {
  c = __builtin_amdgcn_mfma_f32_16x16x32_bf16(
        __builtin_bit_cast(bf16x8, a), __builtin_bit_cast(bf16x8, b), c, 0, 0, 0);
}
// fragment k-offset for slot j (HW-verified R1-R8)
#define KOFF(g, j) (4 * (g) + ((j) & 3) + (((j) >> 2) << 4))

// HK/m201-pattern barrier: NO "memory" clobber anywhere -> backend keeps
// global loads/stores in flight across the barrier (counted vmcnt).
// lgkmcnt(0) guarantees this wave's ds_writes are visible before s_barrier.
static __device__ __forceinline__ void frag_barrier() {
  asm volatile("s_waitcnt lgkmcnt(0)");
  __builtin_amdgcn_s_barrier();
}

__global__ __launch_bounds__(NTHR, 1) void rnn_kernel(
    const float* __restrict__ x, const float* __restrict__ hidden,
    const float* __restrict__ mask, const float* __restrict__ Wi2h,
    const float* __restrict__ bi2h, const float* __restrict__ Wi2o,
    const float* __restrict__ bi2o, float* __restrict__ Y) {

  // [buf][frag: 0..3 = x kk, 4..7 = h kk][lane]; 16 KB
  __shared__ s16x8 sF[2][8][64];

  const int tid = threadIdx.x;
  const int wave = tid >> 6;      // 0..3; owns i2h M-tiles {2w, 2w+1}
  const int lane = tid & 63;
  const int g = lane >> 4;
  const int n16 = lane & 15;
  // chunked XCD swizzle: consecutive data-blocks (sharing 64B x-lines) on one XCD
  const int bid = ((blockIdx.x & 7) << 5) | (blockIdx.x >> 3);
  const int b0 = bid * BT;

  // ---- Wi2h A-frags for tiles 2w, 2w+1 (64 VGPR) ----
  s16x8 W0[8], W1[8];
#pragma unroll
  for (int kt = 0; kt < 8; ++kt) {
    const float* wr0 = Wi2h + (size_t)(16 * (2 * wave + 0) + n16) * (IN_SZ + HID);
    const float* wr1 = Wi2h + (size_t)(16 * (2 * wave + 1) + n16) * (IN_SZ + HID);
    s16x8 w8a, w8b;
#pragma unroll
    for (int j = 0; j < 8; ++j) {
      w8a[j] = (short)f2bf(wr0[32 * kt + KOFF(g, j)]);
      w8b[j] = (short)f2bf(wr1[32 * kt + KOFF(g, j)]);
    }
    W0[kt] = w8a; W1[kt] = w8b;
  }

  // ---- i2o: wave w -> out-tile w (rows 16w..16w+15, all < 64 valid);
  //      wave 3 also out-tile 4 (rows 64..66) ----
  s16x8 wO[4], wO4[4];
#pragma unroll
  for (int kk = 0; kk < 4; ++kk) {
    s16x8 a, b;
#pragma unroll
    for (int j = 0; j < 8; ++j) {
      int m = 16 * wave + n16;
      a[j] = (short)f2bf(Wi2o[(size_t)m * HID + 32 * kk + KOFF(g, j)]);
      int m4 = 64 + n16;
      b[j] = (short)((wave == 3 && m4 < OUT_SZ)
                     ? f2bf(Wi2o[(size_t)m4 * HID + 32 * kk + KOFF(g, j)]) : 0);
    }
    wO[kk] = a; wO4[kk] = b;
  }

  // ---- biases ----
  f32x4 bhv0, bhv1, bov, bov4;
#pragma unroll
  for (int r = 0; r < 4; ++r) {
    bhv0[r] = bi2h[16 * (2 * wave + 0) + 4 * g + r];
    bhv1[r] = bi2h[16 * (2 * wave + 1) + 4 * g + r];
    bov[r] = bi2o[16 * wave + 4 * g + r];
    int m4 = 64 + 4 * g + r;
    bov4[r] = (wave == 3 && m4 < OUT_SZ) ? bi2o[m4] : 0.f;
  }

  // ---- loader mapping: thread -> (col lc, rows 4*lrb..4*lrb+3) ----
  const int lc = tid & 7;
  const int lrb = tid >> 3;                 // 0..31
  const int lkk = lrb >> 3;
  const int lg = lrb & 3;
  const int ljh = (lrb >> 2) & 1;
  const int fragcol = 16 * lg + lc;         // target lane in frag
  const int slot = 4 * ljh;                 // ushort slot base (8B-aligned)
  uint32_t xrow[4];                         // element base: row*SB + b0 + lc
#pragma unroll
  for (int i = 0; i < 4; ++i)
    xrow[i] = (uint32_t)(4 * lrb + i) * (uint32_t)SB + (uint32_t)(b0 + lc);

  // ---- stage x_0 and h_0 = hidden*mask into buf 0 ----
  {
    float v[4], hv[4];
#pragma unroll
    for (int i = 0; i < 4; ++i) {
      v[i] = x[(size_t)xrow[i]];
      uint32_t ho = (uint32_t)(4 * lrb + i) * (uint32_t)BATCH + (uint32_t)(b0 + lc);
      hv[i] = hidden[(size_t)ho] * mask[(size_t)ho];
    }
    unsigned short* px = (unsigned short*)&sF[0][lkk][fragcol] + slot;
    ((uint32_t*)px)[0] = pk2bf(v[0], v[1]);
    ((uint32_t*)px)[1] = pk2bf(v[2], v[3]);
    unsigned short* ph = (unsigned short*)&sF[0][4 + lkk][fragcol] + slot;
    ((uint32_t*)ph)[0] = pk2bf(hv[0], hv[1]);
    ((uint32_t*)ph)[1] = pk2bf(hv[2], hv[3]);
  }
  // 3-deep raw prefetch: xa = x_1, xbr = x_2
  float xa[4], xbr[4];
#pragma unroll
  for (int i = 0; i < 4; ++i) {
    xa[i] = x[(size_t)(xrow[i] + 1u * BATCH)];
    xbr[i] = x[(size_t)(xrow[i] + 2u * BATCH)];
  }
  frag_barrier();

  const uint32_t ybase = (uint32_t)(16 * wave + 4 * g) * (uint32_t)SB + (uint32_t)(b0 + n16);
  const uint32_t yb4 = (uint32_t)(64 + 4 * g) * (uint32_t)SB + (uint32_t)(b0 + n16);

#define STEP(T, P)                                                              \
  {                                                                             \
    const int t = (T);                                                          \
    const int pn = (P) ^ 1;                                                     \
    /* issue x_{t+3} loads (consumed 2 steps later) */                          \
    const uint32_t tn = (uint32_t)((t + 3 > 511) ? 511 : t + 3) * (uint32_t)BATCH; \
    float xn[4];                                                                \
    _Pragma("unroll")                                                           \
    for (int i = 0; i < 4; ++i) xn[i] = x[(size_t)(xrow[i] + tn)];              \
    /* read all frags of [x_t ; h_t] from buf P */                              \
    s16x8 X0 = sF[P][0][lane], X1 = sF[P][1][lane];                             \
    s16x8 X2 = sF[P][2][lane], X3 = sF[P][3][lane];                             \
    s16x8 H0 = sF[P][4][lane], H1 = sF[P][5][lane];                             \
    s16x8 H2 = sF[P][6][lane], H3 = sF[P][7][lane];                             \
    /* i2h: 4 independent chains, depth 4 */                                    \
    f32x4 a = bhv0, a2 = {0.f, 0.f, 0.f, 0.f};                                  \
    f32x4 b = bhv1, b2 = {0.f, 0.f, 0.f, 0.f};                                  \
    mfma16(a, W0[0], X0);  mfma16(a2, W0[1], X1);                               \
    mfma16(b, W1[0], X0);  mfma16(b2, W1[1], X1);                               \
    mfma16(a, W0[2], X2);  mfma16(a2, W0[3], X3);                               \
    mfma16(b, W1[2], X2);  mfma16(b2, W1[3], X3);                               \
    mfma16(a, W0[4], H0);  mfma16(a2, W0[5], H1);                               \
    mfma16(b, W1[4], H0);  mfma16(b2, W1[5], H1);                               \
    mfma16(a, W0[6], H2);  mfma16(a2, W0[7], H3);                               \
    mfma16(b, W1[6], H2);  mfma16(b2, W1[7], H3);                               \
    /* i2o(t-1): independent MFMAs reading buf P h-frags; fills stalls */       \
    if (t > 0) {                                                                \
      const uint32_t ty = (uint32_t)(t - 1) * (uint32_t)BATCH;                  \
      f32x4 ao = bov;                                                           \
      mfma16(ao, wO[0], H0); mfma16(ao, wO[1], H1);                             \
      mfma16(ao, wO[2], H2); mfma16(ao, wO[3], H3);                             \
      if (n16 < 8) {                                                            \
        _Pragma("unroll")                                                       \
        for (int r = 0; r < 4; ++r)                                             \
          Y[(size_t)(ybase + (uint32_t)r * SB + ty)] = fmaxf(ao[r], 0.f);       \
      }                                                                         \
      if (wave == 3) {                                                          \
        f32x4 ao4 = bov4;                                                       \
        mfma16(ao4, wO4[0], H0); mfma16(ao4, wO4[1], H1);                       \
        mfma16(ao4, wO4[2], H2); mfma16(ao4, wO4[3], H3);                       \
        if (n16 < 8 && g == 0) {                                                \
          _Pragma("unroll")                                                     \
          for (int r = 0; r < 3; ++r)                                           \
            Y[(size_t)(yb4 + (uint32_t)r * SB + ty)] = fmaxf(ao4[r], 0.f);      \
        }                                                                       \
      }                                                                         \
    }                                                                           \
    /* h_{t+1} own frag: tanh; D-frag(tiles 2w,2w+1) == B-frag kk=w */          \
    {                                                                           \
      f32x4 s0 = a + a2, s1 = b + b2;                                           \
      union { s16x8 v; uint32_t d[4]; } u;                                      \
      u.d[0] = pk2bf(fast_tanh(s0[0]), fast_tanh(s0[1]));                       \
      u.d[1] = pk2bf(fast_tanh(s0[2]), fast_tanh(s0[3]));                       \
      u.d[2] = pk2bf(fast_tanh(s1[0]), fast_tanh(s1[1]));                       \
      u.d[3] = pk2bf(fast_tanh(s1[2]), fast_tanh(s1[3]));                       \
      sF[pn][4 + wave][lane] = u.v;                                             \
    }                                                                           \
    /* x_{t+1} frag from xa (loaded 2 steps ago) */                             \
    {                                                                           \
      unsigned short* px = (unsigned short*)&sF[pn][lkk][fragcol] + slot;       \
      ((uint32_t*)px)[0] = pk2bf(xa[0], xa[1]);                                 \
      ((uint32_t*)px)[1] = pk2bf(xa[2], xa[3]);                                 \
    }                                                                           \
    _Pragma("unroll")                                                           \
    for (int i = 0; i < 4; ++i) { xa[i] = xbr[i]; xbr[i] = xn[i]; }             \
    frag_barrier();                                                             \
  }

  for (int t2 = 0; t2 < SEQ; t2 += 2) {
    STEP(t2, 0);
    STEP(t2 + 1, 1);
  }
#undef STEP

  // ---- epilogue: y_511 = relu(Wo·h_512 + bo); h_512 frags in buf 0 ----
  {
    s16x8 H0 = sF[0][4][lane], H1 = sF[0][5][lane];
    s16x8 H2 = sF[0][6][lane], H3 = sF[0][7][lane];
    const uint32_t ty = 511u * (uint32_t)BATCH;
    f32x4 ao = bov;
    mfma16(ao, wO[0], H0); mfma16(ao, wO[1], H1);
    mfma16(ao, wO[2], H2); mfma16(ao, wO[3], H3);
    if (n16 < 8) {
#pragma unroll
      for (int r = 0; r < 4; ++r)
        Y[(size_t)(ybase + (uint32_t)r * SB + ty)] = fmaxf(ao[r], 0.f);
    }
    if (wave == 3) {
      f32x4 ao4 = bov4;
      mfma16(ao4, wO4[0], H0); mfma16(ao4, wO4[1], H1);
      mfma16(ao4, wO4[2], H2); mfma16(ao4, wO4[3], H3);
      if (n16 < 8 && g == 0) {
#pragma unroll
        for (int r = 0; r < 3; ++r)
          Y[(size_t)(yb4 + (uint32_t)r * SB + ty)] = fmaxf(ao4[r], 0.f);
      }
    }
  }
}

extern "C" void kernel_launch(void* const* d_in, const int* in_sizes, int n_in,
                              void* d_out, int out_size, void* d_ws, size_t ws_size,
                              hipStream_t stream) {
  const float* x      = (const float*)d_in[0];
  const float* hidden = (const float*)d_in[1];
  const float* mask   = (const float*)d_in[2];
  const float* Wi2h   = (const float*)d_in[3];
  const float* bi2h   = (const float*)d_in[4];
  const float* Wi2o   = (const float*)d_in[5];
  const float* bi2o   = (const float*)d_in[6];
  float* Y = (float*)d_out;
  (void)in_sizes; (void)n_in; (void)out_size; (void)d_ws; (void)ws_size;
  rnn_kernel<<<dim3(BATCH / BT), dim3(NTHR), 0, stream>>>(
      x, hidden, mask, Wi2h, bi2h, Wi2o, bi2o, Y);
}

// Round 10
// 545.535 us; speedup vs baseline: 3.5298x; 1.0346x over previous
//
#include <hip/hip_runtime.h>
#include <hip/hip_bf16.h>
#include <stdint.h>

#define IN_SZ 128
#define HID 128
#define OUT_SZ 67
#define SEQ 512
#define BATCH 2048
#define BT 8
#define NTHR 256
#define SB (SEQ * BATCH)   // 1048576

typedef __attribute__((ext_vector_type(4))) float f32x4;
typedef __attribute__((ext_vector_type(8))) short s16x8;
typedef __attribute__((ext_vector_type(8))) __bf16 bf16x8;

static __device__ __forceinline__ unsigned short f2bf(float f) {
  union { float f; uint32_t u; } c; c.f = f;
  uint32_t u = c.u;
  uint32_t r = u + 0x7FFFu + ((u >> 16) & 1u);
  return (unsigned short)(r >> 16);
}
static __device__ __forceinline__ uint32_t pk2bf(float lo, float hi) {
  __hip_bfloat162 h2 = __float22bfloat162_rn(float2{lo, hi});
  union { __hip_bfloat162 h; uint32_t u; } c; c.h = h2;
  return c.u;
}
static __device__ __forceinline__ float fast_tanh(float x) {
  float e = __builtin_amdgcn_exp2f(x * 2.885390081777927f);
  float r = __builtin_amdgcn_rcpf(e + 1.f);
  return __builtin_fmaf(-2.f, r, 1.f);
}
static __device__ __forceinline__ void mfma16(f32x4& c, s16x8 a, s16x8 b) {
  c = __builtin_amdgcn_mfma_f32_16x16x32_bf16(
        __builtin_bit_cast(bf16x8, a), __builtin_bit_cast(bf16x8, b), c, 0, 0, 0);
}
#define KOFF(g, j) (4 * (g) + ((j) & 3) + (((j) >> 2) << 4))

// clobber-free barrier (validated R9): ds_writes ordered by lgkmcnt(0);
// global loads/stores stay in flight across s_barrier (counted vmcnt).
static __device__ __forceinline__ void frag_barrier() {
  asm volatile("s_waitcnt lgkmcnt(0)");
  __builtin_amdgcn_s_barrier();
}

__global__ __launch_bounds__(NTHR, 1) void rnn_kernel(
    const float* __restrict__ x, const float* __restrict__ hidden,
    const float* __restrict__ mask, const float* __restrict__ Wi2h,
    const float* __restrict__ bi2h, const float* __restrict__ Wi2o,
    const float* __restrict__ bi2o, float* __restrict__ Y) {

  __shared__ s16x8 sF[2][8][64];   // [buf][0..3 x kk, 4..7 h kk][lane]

  const int tid = threadIdx.x;
  const int wave = tid >> 6;
  const int lane = tid & 63;
  const int g = lane >> 4;
  const int n16 = lane & 15;
  const int bid = ((blockIdx.x & 7) << 5) | (blockIdx.x >> 3);  // XCD-chunk swizzle
  const int b0 = bid * BT;

  // ---- Wi2h A-frags for tiles 2w, 2w+1 ----
  s16x8 W0[8], W1[8];
#pragma unroll
  for (int kt = 0; kt < 8; ++kt) {
    const float* wr0 = Wi2h + (size_t)(16 * (2 * wave + 0) + n16) * (IN_SZ + HID);
    const float* wr1 = Wi2h + (size_t)(16 * (2 * wave + 1) + n16) * (IN_SZ + HID);
    s16x8 w8a, w8b;
#pragma unroll
    for (int j = 0; j < 8; ++j) {
      w8a[j] = (short)f2bf(wr0[32 * kt + KOFF(g, j)]);
      w8b[j] = (short)f2bf(wr1[32 * kt + KOFF(g, j)]);
    }
    W0[kt] = w8a; W1[kt] = w8b;
  }

  // ---- i2o frags: wave w -> out-tile w; wave 3 also tile 4 (rows 64..66) ----
  s16x8 wO[4], wO4[4];
#pragma unroll
  for (int kk = 0; kk < 4; ++kk) {
    s16x8 a, b;
#pragma unroll
    for (int j = 0; j < 8; ++j) {
      int m = 16 * wave + n16;
      a[j] = (short)f2bf(Wi2o[(size_t)m * HID + 32 * kk + KOFF(g, j)]);
      int m4 = 64 + n16;
      b[j] = (short)((wave == 3 && m4 < OUT_SZ)
                     ? f2bf(Wi2o[(size_t)m4 * HID + 32 * kk + KOFF(g, j)]) : 0);
    }
    wO[kk] = a; wO4[kk] = b;
  }

  f32x4 bhv0, bhv1, bov, bov4;
#pragma unroll
  for (int r = 0; r < 4; ++r) {
    bhv0[r] = bi2h[16 * (2 * wave + 0) + 4 * g + r];
    bhv1[r] = bi2h[16 * (2 * wave + 1) + 4 * g + r];
    bov[r] = bi2o[16 * wave + 4 * g + r];
    int m4 = 64 + 4 * g + r;
    bov4[r] = (wave == 3 && m4 < OUT_SZ) ? bi2o[m4] : 0.f;
  }

  // ---- loader mapping: thread -> (col lc, rows 4*lrb..4*lrb+3) ----
  const int lc = tid & 7;
  const int lrb = tid >> 3;
  const int lkk = lrb >> 3;
  const int lg = lrb & 3;
  const int ljh = (lrb >> 2) & 1;
  const int fragcol = 16 * lg + lc;
  const int slot = 4 * ljh;
  const char* const xB = (const char*)x;
  uint32_t xrb[4];                          // byte offsets: (row*SB + b0 + lc)*4
#pragma unroll
  for (int i = 0; i < 4; ++i)
    xrb[i] = ((uint32_t)(4 * lrb + i) * (uint32_t)SB + (uint32_t)(b0 + lc)) * 4u;

  // ---- stage x_0, h_0 into buf 0 ----
  {
    float v[4], hv[4];
#pragma unroll
    for (int i = 0; i < 4; ++i) {
      v[i] = *(const float*)(xB + xrb[i]);
      uint32_t ho = (uint32_t)(4 * lrb + i) * (uint32_t)BATCH + (uint32_t)(b0 + lc);
      hv[i] = hidden[(size_t)ho] * mask[(size_t)ho];
    }
    unsigned short* px = (unsigned short*)&sF[0][lkk][fragcol] + slot;
    ((uint32_t*)px)[0] = pk2bf(v[0], v[1]);
    ((uint32_t*)px)[1] = pk2bf(v[2], v[3]);
    unsigned short* ph = (unsigned short*)&sF[0][4 + lkk][fragcol] + slot;
    ((uint32_t*)ph)[0] = pk2bf(hv[0], hv[1]);
    ((uint32_t*)ph)[1] = pk2bf(hv[2], hv[3]);
  }
  // ---- 4 named prefetch buffers: xq0=x_1, xq1=x_2, xq2=x_3, xq3=x_4 ----
  float xq0[4], xq1[4], xq2[4], xq3[4];
#pragma unroll
  for (int i = 0; i < 4; ++i) {
    xq0[i] = *(const float*)(xB + xrb[i] + 1u * BATCH * 4u);
    xq1[i] = *(const float*)(xB + xrb[i] + 2u * BATCH * 4u);
    xq2[i] = *(const float*)(xB + xrb[i] + 3u * BATCH * 4u);
    xq3[i] = *(const float*)(xB + xrb[i] + 4u * BATCH * 4u);
  }
  frag_barrier();

  const uint32_t ybase = (uint32_t)(16 * wave + 4 * g) * (uint32_t)SB + (uint32_t)(b0 + n16);
  const uint32_t yb4 = (uint32_t)(64 + 4 * g) * (uint32_t)SB + (uint32_t)(b0 + n16);

#define STEP(T, P, XQ)                                                          \
  {                                                                             \
    const int t = (T);                                                          \
    const int pn = (P) ^ 1;                                                     \
    /* 1. stage x_{t+1} frag from XQ (loaded 4 steps ago; vmcnt wait here) */   \
    {                                                                           \
      unsigned short* px = (unsigned short*)&sF[pn][lkk][fragcol] + slot;       \
      ((uint32_t*)px)[0] = pk2bf(XQ[0], XQ[1]);                                 \
      ((uint32_t*)px)[1] = pk2bf(XQ[2], XQ[3]);                                 \
    }                                                                           \
    /* 2. reissue loads x_{t+5} into XQ (no copies: consume-then-overwrite) */  \
    {                                                                           \
      const uint32_t tn = (uint32_t)((t + 5 > 511) ? 511 : t + 5) * (BATCH * 4u); \
      _Pragma("unroll")                                                         \
      for (int i = 0; i < 4; ++i) XQ[i] = *(const float*)(xB + xrb[i] + tn);    \
    }                                                                           \
    /* 3. frags of [x_t ; h_t] from buf P */                                    \
    s16x8 X0 = sF[P][0][lane], X1 = sF[P][1][lane];                             \
    s16x8 X2 = sF[P][2][lane], X3 = sF[P][3][lane];                             \
    s16x8 H0 = sF[P][4][lane], H1 = sF[P][5][lane];                             \
    s16x8 H2 = sF[P][6][lane], H3 = sF[P][7][lane];                             \
    /* 4. i2h: 4 independent chains, depth 4 */                                 \
    f32x4 a = bhv0, a2 = {0.f, 0.f, 0.f, 0.f};                                  \
    f32x4 b = bhv1, b2 = {0.f, 0.f, 0.f, 0.f};                                  \
    mfma16(a, W0[4], H0);  mfma16(a2, W0[5], H1);                               \
    mfma16(b, W1[4], H0);  mfma16(b2, W1[5], H1);                               \
    mfma16(a, W0[6], H2);  mfma16(a2, W0[7], H3);                               \
    mfma16(b, W1[6], H2);  mfma16(b2, W1[7], H3);                               \
    mfma16(a, W0[0], X0);  mfma16(a2, W0[1], X1);                               \
    mfma16(b, W1[0], X0);  mfma16(b2, W1[1], X1);                               \
    mfma16(a, W0[2], X2);  mfma16(a2, W0[3], X3);                               \
    mfma16(b, W1[2], X2);  mfma16(b2, W1[3], X3);                               \
    /* 5. i2o(t-1) */                                                           \
    if (t > 0) {                                                                \
      const uint32_t ty = (uint32_t)(t - 1) * (uint32_t)BATCH;                  \
      f32x4 ao = bov;                                                           \
      mfma16(ao, wO[0], H0); mfma16(ao, wO[1], H1);                             \
      mfma16(ao, wO[2], H2); mfma16(ao, wO[3], H3);                             \
      if (n16 < 8) {                                                            \
        _Pragma("unroll")                                                       \
        for (int r = 0; r < 4; ++r)                                             \
          Y[(size_t)(ybase + (uint32_t)r * SB + ty)] = fmaxf(ao[r], 0.f);       \
      }                                                                         \
      if (wave == 3) {                                                          \
        f32x4 ao4 = bov4;                                                       \
        mfma16(ao4, wO4[0], H0); mfma16(ao4, wO4[1], H1);                       \
        mfma16(ao4, wO4[2], H2); mfma16(ao4, wO4[3], H3);                       \
        if (n16 < 8 && g == 0) {                                                \
          _Pragma("unroll")                                                     \
          for (int r = 0; r < 3; ++r)                                           \
            Y[(size_t)(yb4 + (uint32_t)r * SB + ty)] = fmaxf(ao4[r], 0.f);      \
        }                                                                       \
      }                                                                         \
    }                                                                           \
    /* 6. h_{t+1}: tanh; D-frag(tiles 2w,2w+1) == B-frag kk=w */                \
    {                                                                           \
      f32x4 s0 = a + a2, s1 = b + b2;                                           \
      union { s16x8 v; uint32_t d[4]; } u;                                      \
      u.d[0] = pk2bf(fast_tanh(s0[0]), fast_tanh(s0[1]));                       \
      u.d[1] = pk2bf(fast_tanh(s0[2]), fast_tanh(s0[3]));                       \
      u.d[2] = pk2bf(fast_tanh(s1[0]), fast_tanh(s1[1]));                       \
      u.d[3] = pk2bf(fast_tanh(s1[2]), fast_tanh(s1[3]));                       \
      sF[pn][4 + wave][lane] = u.v;                                             \
    }                                                                           \
    frag_barrier();                                                             \
  }

  for (int t4 = 0; t4 < SEQ; t4 += 4) {
    STEP(t4 + 0, 0, xq0);
    STEP(t4 + 1, 1, xq1);
    STEP(t4 + 2, 0, xq2);
    STEP(t4 + 3, 1, xq3);
  }
#undef STEP

  // ---- epilogue: y_511 from h_512 (buf 0) ----
  {
    s16x8 H0 = sF[0][4][lane], H1 = sF[0][5][lane];
    s16x8 H2 = sF[0][6][lane], H3 = sF[0][7][lane];
    const uint32_t ty = 511u * (uint32_t)BATCH;
    f32x4 ao = bov;
    mfma16(ao, wO[0], H0); mfma16(ao, wO[1], H1);
    mfma16(ao, wO[2], H2); mfma16(ao, wO[3], H3);
    if (n16 < 8) {
#pragma unroll
      for (int r = 0; r < 4; ++r)
        Y[(size_t)(ybase + (uint32_t)r * SB + ty)] = fmaxf(ao[r], 0.f);
    }
    if (wave == 3) {
      f32x4 ao4 = bov4;
      mfma16(ao4, wO4[0], H0); mfma16(ao4, wO4[1], H1);
      mfma16(ao4, wO4[2], H2); mfma16(ao4, wO4[3], H3);
      if (n16 < 8 && g == 0) {
#pragma unroll
        for (int r = 0; r < 3; ++r)
          Y[(size_t)(yb4 + (uint32_t)r * SB + ty)] = fmaxf(ao4[r], 0.f);
      }
    }
  }
}

extern "C" void kernel_launch(void* const* d_in, const int* in_sizes, int n_in,
                              void* d_out, int out_size, void* d_ws, size_t ws_size,
                              hipStream_t stream) {
  const float* x      = (const float*)d_in[0];
  const float* hidden = (const float*)d_in[1];
  const float* mask   = (const float*)d_in[2];
  const float* Wi2h   = (const float*)d_in[3];
  const float* bi2h   = (const float*)d_in[4];
  const float* Wi2o   = (const float*)d_in[5];
  const float* bi2o   = (const float*)d_in[6];
  float* Y = (float*)d_out;
  (void)in_sizes; (void)n_in; (void)out_size; (void)d_ws; (void)ws_size;
  rnn_kernel<<<dim3(BATCH / BT), dim3(NTHR), 0, stream>>>(
      x, hidden, mask, Wi2h, bi2h, Wi2o, bi2o, Y);
}